// Round 7
// baseline (1257.121 us; speedup 1.0000x reference)
//
#include <hip/hip_runtime.h>

typedef __bf16 bf16;
typedef __bf16 bf16x2 __attribute__((ext_vector_type(2)));
typedef __bf16 bf16x4 __attribute__((ext_vector_type(4)));
typedef __bf16 bf16x8 __attribute__((ext_vector_type(8)));
typedef float f32x4 __attribute__((ext_vector_type(4)));

#define NN 50000
#define NE 800000
#define EMB 128
#define EDGE_F 16
#define NLAYER 5
#define SCAN_BLOCKS 196   // ceil(50000/256)
// slice-major layout: [8 slices][NN nodes][16 ch], slice = ch >> 4
#define NPC 64                              // nodes per agg block (256 thr / 4 lanes)
#define NCHUNK ((NN + NPC - 1) / NPC)       // 782
#define GEMM_GRID 391                       // B-stationary GEMM blocks

// ---------------------------------------------------------------------------
// Weight swizzle + fp32->bf16: row-major [K][N] -> [(k/32)][n][k%32] so an
// MFMA B-fragment (n = lane&15, k = (lane>>4)*8 + j) is one contiguous 16B.
// ---------------------------------------------------------------------------
__global__ __launch_bounds__(256) void swz_kernel(
    const float* __restrict__ Wx, const float* __restrict__ W1,
    const float* __restrict__ W2,
    bf16* __restrict__ wx_s, bf16* __restrict__ w1_s, bf16* __restrict__ w2_s)
{
    int t = blockIdx.x * 256 + threadIdx.x;
    if (t < 16384) {                                   // Wx: K=128,N=128
        int k = t >> 7, n = t & 127;
        wx_s[(((k >> 5) << 7) + n) * 32 + (k & 31)] = (bf16)Wx[t];
    } else if (t < 16384 + 163840) {                   // W1: 5 x (K=128,N=256)
        int u = t - 16384;
        int l = u / 32768, r = u % 32768;
        int k = r >> 8, n = r & 255;
        w1_s[l * 32768 + (((k >> 5) << 8) + n) * 32 + (k & 31)] = (bf16)W1[u];
    } else if (t < 16384 + 327680) {                   // W2: 5 x (K=256,N=128)
        int u = t - (16384 + 163840);
        int l = u / 32768, r = u % 32768;
        int k = r >> 7, n = r & 127;
        w2_s[l * 32768 + (((k >> 5) << 7) + n) * 32 + (k & 31)] = (bf16)W2[u];
    }
}

// ---------------------------------------------------------------------------
// CSR build: count -> hierarchical scan -> fill
// ---------------------------------------------------------------------------
__global__ void count_kernel(const int* __restrict__ dst, int* __restrict__ deg, int nE)
{
    int e = blockIdx.x * 256 + threadIdx.x;
    if (e < nE) atomicAdd(&deg[dst[e]], 1);
}

__global__ __launch_bounds__(256) void deg_bsum_kernel(
    const int* __restrict__ deg, int* __restrict__ bsum, int n)
{
    __shared__ int red[256];
    int i = blockIdx.x * 256 + threadIdx.x;
    red[threadIdx.x] = (i < n) ? deg[i] : 0;
    __syncthreads();
    for (int s = 128; s > 0; s >>= 1) {
        if (threadIdx.x < s) red[threadIdx.x] += red[threadIdx.x + s];
        __syncthreads();
    }
    if (threadIdx.x == 0) bsum[blockIdx.x] = red[0];
}

__global__ __launch_bounds__(256) void bsum_scan_kernel(
    const int* __restrict__ bsum, int* __restrict__ boff,
    int* __restrict__ rowstart, int nb, int n)
{
    __shared__ int v[256];
    int t = threadIdx.x;
    v[t] = (t < nb) ? bsum[t] : 0;
    __syncthreads();
    if (t == 0) {
        int r = 0;
        for (int i = 0; i < nb; ++i) { int x = v[i]; v[i] = r; r += x; }
        rowstart[n] = r;
    }
    __syncthreads();
    if (t < nb) boff[t] = v[t];
}

__global__ __launch_bounds__(256) void chunk_scan_kernel(
    const int* __restrict__ deg, const int* __restrict__ boff,
    int* __restrict__ rowstart, int* __restrict__ cursor, int n)
{
    __shared__ int v[256];
    int t = threadIdx.x;
    int i = blockIdx.x * 256 + t;
    int x = (i < n) ? deg[i] : 0;
    v[t] = x;
    __syncthreads();
    for (int s = 1; s < 256; s <<= 1) {
        int add = (t >= s) ? v[t - s] : 0;
        __syncthreads();
        v[t] += add;
        __syncthreads();
    }
    int ex = v[t] - x + boff[blockIdx.x];
    if (i < n) { rowstart[i] = ex; cursor[i] = ex; }
}

__global__ void fill_kernel(const int* __restrict__ src, const int* __restrict__ dst,
                            int* __restrict__ cursor, int* __restrict__ csr_src,
                            int* __restrict__ csr_e, int nE)
{
    int e = blockIdx.x * 256 + threadIdx.x;
    if (e < nE) {
        int d = dst[e];
        int pos = atomicAdd(&cursor[d], 1);
        csr_src[pos] = src[e];
        csr_e[pos] = e;
    }
}

// ---------------------------------------------------------------------------
// ea_agg[i][f] = sum over in-edges of edge_attr[e][f]. fp64 accumulation so
// the (nondeterministic) CSR slot order cannot perturb the fp32 result.
// ---------------------------------------------------------------------------
__global__ __launch_bounds__(256) void ea_gather_kernel(
    const float* __restrict__ edge_attr, const int* __restrict__ rowstart,
    const int* __restrict__ csr_e, float* __restrict__ ea_agg, int n)
{
    int node = blockIdx.x * 16 + (threadIdx.x >> 4);
    int f = threadIdx.x & 15;
    if (node >= n) return;
    int rs = rowstart[node], re = rowstart[node + 1];
    double a = 0.0;
    for (int j = rs; j < re; ++j) {
        int e = csr_e[j];
        a += (double)edge_attr[(size_t)e * EDGE_F + f];
    }
    ea_agg[node * EDGE_F + f] = (float)a;
}

// ---------------------------------------------------------------------------
// agg[slice][i][c] = sum_{e:dst=i} h[src_e] + h[i] + ea_agg[i]@We + (deg+1)*be
// Deterministic blockIdx%8 slicing (r5's measured-good locality variant; the
// r6 getreg+steal queue caused unexplained divergence + 2x slowdown — removed).
// fp64 edge accumulation -> bit-deterministic under CSR-order races.
// 4 lanes per node (bf16x4 gathers), 64 nodes per block.
// ---------------------------------------------------------------------------
__global__ __launch_bounds__(256) void agg_kernel(
    const bf16* __restrict__ hsm, const int* __restrict__ rowstart,
    const int* __restrict__ csr_src, const float* __restrict__ ea_agg,
    const float* __restrict__ We_l, const float* __restrict__ be_l,
    bf16* __restrict__ aggb)
{
    const int tid = threadIdx.x;
    const int slice = blockIdx.x & 7;
    const int chunk = blockIdx.x >> 3;
    const int node = chunk * NPC + (tid >> 2);
    const int ql = tid & 3;                  // 4 channels per lane
    if (node >= NN) return;
    const size_t sbase = (size_t)slice * NN * 16;
    const bf16* hs = hsm + sbase + ql * 4;
    const int cs = slice * 16 + ql * 4;      // global channel base
    const int rs = rowstart[node], re = rowstart[node + 1];

    double d0 = 0.0, d1 = 0.0, d2 = 0.0, d3 = 0.0;
    int j = rs;
    for (; j + 4 <= re; j += 4) {
        int s0 = csr_src[j],     s1 = csr_src[j + 1];
        int s2 = csr_src[j + 2], s3 = csr_src[j + 3];
        bf16x4 r0 = *(const bf16x4*)(hs + (size_t)s0 * 16);
        bf16x4 r1 = *(const bf16x4*)(hs + (size_t)s1 * 16);
        bf16x4 r2 = *(const bf16x4*)(hs + (size_t)s2 * 16);
        bf16x4 r3 = *(const bf16x4*)(hs + (size_t)s3 * 16);
        d0 += ((double)(float)r0.x + (double)(float)r1.x)
            + ((double)(float)r2.x + (double)(float)r3.x);
        d1 += ((double)(float)r0.y + (double)(float)r1.y)
            + ((double)(float)r2.y + (double)(float)r3.y);
        d2 += ((double)(float)r0.z + (double)(float)r1.z)
            + ((double)(float)r2.z + (double)(float)r3.z);
        d3 += ((double)(float)r0.w + (double)(float)r1.w)
            + ((double)(float)r2.w + (double)(float)r3.w);
    }
    for (; j < re; ++j) {
        int s = csr_src[j];
        bf16x4 rv = *(const bf16x4*)(hs + (size_t)s * 16);
        d0 += (double)(float)rv.x; d1 += (double)(float)rv.y;
        d2 += (double)(float)rv.z; d3 += (double)(float)rv.w;
    }
    {   // self loop
        bf16x4 rv = *(const bf16x4*)(hs + (size_t)node * 16);
        d0 += (double)(float)rv.x; d1 += (double)(float)rv.y;
        d2 += (double)(float)rv.z; d3 += (double)(float)rv.w;
    }
    f32x4 acc;
    acc.x = (float)d0; acc.y = (float)d1; acc.z = (float)d2; acc.w = (float)d3;
    // + ea_agg[node] @ We[:, cs..cs+3]  (We row-major [16][128], L1-hot)
    const float* ea = ea_agg + (size_t)node * EDGE_F;
#pragma unroll
    for (int f = 0; f < EDGE_F; ++f) {
        f32x4 w = *(const f32x4*)(We_l + f * EMB + cs);
        float ef = ea[f];
        acc.x += ef * w.x; acc.y += ef * w.y;
        acc.z += ef * w.z; acc.w += ef * w.w;
    }
    const f32x4 bev = *(const f32x4*)(be_l + cs);
    float dp1 = (float)(re - rs + 1);
    acc.x += dp1 * bev.x; acc.y += dp1 * bev.y;
    acc.z += dp1 * bev.z; acc.w += dp1 * bev.w;
    bf16x4 o;
    o.x = (bf16)acc.x; o.y = (bf16)acc.y; o.z = (bf16)acc.z; o.w = (bf16)acc.w;
    *(bf16x4*)(aggb + sbase + (size_t)node * 16 + ql * 4) = o;
}

// ---------------------------------------------------------------------------
// B-STATIONARY GEMM: whole pre-swizzled B (<=64KB) staged to LDS once per
// block; waves grid-stride over 16-row strips (3125 strips, M=50000 exactly
// divisible -> no row guards). B-fragments come from ds_read_b128 instead of
// per-wave L2 round-trips (rounds 2-5: GEMMs ran ~10x over their memory
// floor, L2-latency bound). STATS: deterministic register accumulation per
// block -> psum row (no atomics).
// ---------------------------------------------------------------------------
template <int K, int N, bool RELU, bool AFP32, bool STATS, bool ASM, bool OSM>
__global__ __launch_bounds__(256) void gemm_kernel(
    const void* __restrict__ Ap, const bf16* __restrict__ Bswz,
    const float* __restrict__ bias, bf16* __restrict__ outp,
    float* __restrict__ psum, int M)
{
    __shared__ bf16 Bl[K * N];
    __shared__ float lstat[STATS ? 1024 : 1];
    for (int i = threadIdx.x; i < K * N / 8; i += 256)
        ((bf16x8*)Bl)[i] = ((const bf16x8*)Bswz)[i];
    __syncthreads();

    const int lane = threadIdx.x & 63;
    const int wave = threadIdx.x >> 6;
    const int m = lane & 15, q = lane >> 4;
    constexpr int NF = N / 16, KB = K / 32;
    const int S = M >> 4;                    // 3125 strips

    float sacc1[STATS ? NF : 1];
    float sacc2[STATS ? NF : 1];
    if constexpr (STATS) {
#pragma unroll
        for (int f = 0; f < NF; ++f) { sacc1[f] = 0.f; sacc2[f] = 0.f; }
    }

    for (int s = blockIdx.x * 4 + wave; s < S; s += gridDim.x * 4) {
        const int m0 = s * 16;
        f32x4 acc[NF];
#pragma unroll
        for (int f = 0; f < NF; ++f) acc[f] = 0.f;

#pragma unroll
        for (int kb = 0; kb < KB; ++kb) {
            bf16x8 a;
            if constexpr (AFP32) {
                const float* ar = (const float*)Ap + (size_t)(m0 + m) * K + kb * 32 + q * 8;
                f32x4 v0 = *(const f32x4*)ar;
                f32x4 v1 = *(const f32x4*)(ar + 4);
#pragma unroll
                for (int jj = 0; jj < 4; ++jj) { a[jj] = (bf16)v0[jj]; a[4 + jj] = (bf16)v1[jj]; }
            } else if constexpr (ASM) {
                // slice-major A: channels kb*32+q*8 live in slice 2kb+(q>>1)
                const bf16* ar = (const bf16*)Ap
                    + ((size_t)(kb * 2 + (q >> 1)) * M + (m0 + m)) * 16 + (q & 1) * 8;
                a = *(const bf16x8*)ar;
            } else {
                const bf16* ar = (const bf16*)Ap + (size_t)(m0 + m) * K + kb * 32 + q * 8;
                a = *(const bf16x8*)ar;
            }
#pragma unroll
            for (int f = 0; f < NF; ++f) {
                bf16x8 b = *(const bf16x8*)(Bl + (size_t)(kb * N + f * 16 + m) * 32 + q * 8);
                acc[f] = __builtin_amdgcn_mfma_f32_16x16x32_bf16(a, b, acc[f], 0, 0, 0);
            }
        }

#pragma unroll
        for (int f = 0; f < NF; ++f) {
            const int col = f * 16 + m;
            float bv = bias[col];
#pragma unroll
            for (int r = 0; r < 4; ++r) {
                float v = acc[f][r] + bv;
                if (RELU) v = fmaxf(v, 0.f);
                int row = m0 + q * 4 + r;
                if constexpr (OSM)
                    outp[((size_t)f * M + row) * 16 + m] = (bf16)v;
                else
                    outp[(size_t)row * N + col] = (bf16)v;
                if constexpr (STATS) { sacc1[f] += v; sacc2[f] += v * v; }
            }
        }
    }

    if constexpr (STATS) {
#pragma unroll
        for (int f = 0; f < NF; ++f) {
            float s1 = sacc1[f], s2 = sacc2[f];
            s1 += __shfl_xor(s1, 16); s1 += __shfl_xor(s1, 32);
            s2 += __shfl_xor(s2, 16); s2 += __shfl_xor(s2, 32);
            if (q == 0) {
                lstat[wave * 128 + f * 16 + m] = s1;
                lstat[512 + wave * 128 + f * 16 + m] = s2;
            }
        }
        __syncthreads();
        int t = threadIdx.x;
        if (t < 128) {
            float s = lstat[t] + lstat[128 + t] + lstat[256 + t] + lstat[384 + t];
            float ssq = lstat[512 + t] + lstat[640 + t] + lstat[768 + t] + lstat[896 + t];
            psum[(size_t)blockIdx.x * 256 + t] = s;
            psum[(size_t)blockIdx.x * 256 + 128 + t] = ssq;
        }
    }
}

// ---------------------------------------------------------------------------
// Deterministic stats reduce: 1 block, no atomics. psum rows = [sums|sumsq].
// ---------------------------------------------------------------------------
__global__ __launch_bounds__(256) void reduce_stats_kernel(
    const float* __restrict__ psum, float* __restrict__ stats, int nblk)
{
    int c = threadIdx.x;
    float acc = 0.f;
    for (int b = 0; b < nblk; ++b)
        acc += psum[(size_t)b * 256 + c];
    stats[c] = acc;
}

// ---------------------------------------------------------------------------
// BatchNorm normalize (+optional relu). sm selects slice-major channel decode
// (intermediate layers) vs row-major (final layer, fp32 d_out).
// ---------------------------------------------------------------------------
__global__ __launch_bounds__(256) void norm_kernel(
    const bf16* __restrict__ h2, const float* __restrict__ sums,
    const float* __restrict__ sumsq, const float* __restrict__ gamma,
    const float* __restrict__ beta, void* __restrict__ outp,
    int relu, int out_fp32, int sm)
{
    __shared__ float sc[EMB], sh[EMB];
    int tid = threadIdx.x;
    if (tid < EMB) {
        float inv_n = 1.0f / (float)NN;
        float mean = sums[tid] * inv_n;
        float var = sumsq[tid] * inv_n - mean * mean;
        float s = gamma[tid] * rsqrtf(var + 1e-5f);
        sc[tid] = s;
        sh[tid] = beta[tid] - mean * s;
    }
    __syncthreads();
    const int total4 = NN * (EMB / 4);
    int stride = gridDim.x * blockDim.x;
    for (int i = blockIdx.x * blockDim.x + tid; i < total4; i += stride) {
        bf16x4 hv = ((const bf16x4*)h2)[i];
        int c0;
        if (sm) {
            int o = i * 4;
            int slice = o / (NN * 16);
            c0 = slice * 16 + ((o - slice * (NN * 16)) & 15);
        } else {
            c0 = (i * 4) & (EMB - 1);
        }
        float v0 = (float)hv.x * sc[c0] + sh[c0];
        float v1 = (float)hv.y * sc[c0 + 1] + sh[c0 + 1];
        float v2 = (float)hv.z * sc[c0 + 2] + sh[c0 + 2];
        float v3 = (float)hv.w * sc[c0 + 3] + sh[c0 + 3];
        if (relu) {
            v0 = fmaxf(v0, 0.f); v1 = fmaxf(v1, 0.f);
            v2 = fmaxf(v2, 0.f); v3 = fmaxf(v3, 0.f);
        }
        if (out_fp32) {
            f32x4 o; o.x = v0; o.y = v1; o.z = v2; o.w = v3;
            ((f32x4*)outp)[i] = o;
        } else {
            bf16x4 o;
            o.x = (bf16)v0; o.y = (bf16)v1; o.z = (bf16)v2; o.w = (bf16)v3;
            ((bf16x4*)outp)[i] = o;
        }
    }
}

// ---------------------------------------------------------------------------
extern "C" void kernel_launch(void* const* d_in, const int* in_sizes, int n_in,
                              void* d_out, int out_size, void* d_ws, size_t ws_size,
                              hipStream_t stream)
{
    const float* x         = (const float*)d_in[0];
    const float* edge_attr = (const float*)d_in[1];
    const int*   eidx      = (const int*)d_in[2];
    const float* Wx        = (const float*)d_in[3];
    const float* bx        = (const float*)d_in[4];
    const float* We        = (const float*)d_in[5];
    const float* be        = (const float*)d_in[6];
    const float* W1        = (const float*)d_in[7];
    const float* b1        = (const float*)d_in[8];
    const float* W2        = (const float*)d_in[9];
    const float* b2        = (const float*)d_in[10];
    const float* gamma     = (const float*)d_in[11];
    const float* beta      = (const float*)d_in[12];

    // ---- workspace layout (poisoned 0xAA before every call) ----
    size_t off = 0;
    char* base = (char*)d_ws;
    auto alloc = [&](size_t bytes) -> void* {
        void* p = base + off;
        off += (bytes + 255) & ~(size_t)255;
        return p;
    };
    int*   deg      = (int*)alloc(NN * 4);
    size_t zero_bytes = off;                             // only deg needs zeroing
    float* stats    = (float*)alloc(NLAYER * 256 * 4);   // written (=) by reduce
    int*   rowstart = (int*)alloc((NN + 1) * 4);
    int*   cursor   = (int*)alloc(NN * 4);
    int*   bsum     = (int*)alloc(SCAN_BLOCKS * 4);
    int*   boff     = (int*)alloc(SCAN_BLOCKS * 4);
    int*   csr_src  = (int*)alloc((size_t)NE * 4);
    int*   csr_e    = (int*)alloc((size_t)NE * 4);
    float* ea_agg   = (float*)alloc((size_t)NN * EDGE_F * 4);
    bf16*  h        = (bf16*)alloc((size_t)NN * EMB * 2);   // slice-major
    bf16*  aggb     = (bf16*)alloc((size_t)NN * EMB * 2);   // slice-major
    bf16*  t1       = (bf16*)alloc((size_t)NN * 2 * EMB * 2);
    bf16*  h2b      = (bf16*)alloc((size_t)NN * EMB * 2);   // sm (l<4) / rm (l=4)
    float* psum     = (float*)alloc((size_t)GEMM_GRID * 256 * 4);
    bf16*  wx_s     = (bf16*)alloc(16384 * 2);
    bf16*  w1_s     = (bf16*)alloc(163840 * 2);
    bf16*  w2_s     = (bf16*)alloc(163840 * 2);
    (void)ws_size; (void)in_sizes; (void)n_in; (void)out_size;

    const int* src = eidx;
    const int* dst = eidx + NE;

    hipMemsetAsync(d_ws, 0, zero_bytes, stream);

    swz_kernel<<<1344, 256, 0, stream>>>(Wx, W1, W2, wx_s, w1_s, w2_s);
    count_kernel<<<NE / 256, 256, 0, stream>>>(dst, deg, NE);
    deg_bsum_kernel<<<SCAN_BLOCKS, 256, 0, stream>>>(deg, bsum, NN);
    bsum_scan_kernel<<<1, 256, 0, stream>>>(bsum, boff, rowstart, SCAN_BLOCKS, NN);
    chunk_scan_kernel<<<SCAN_BLOCKS, 256, 0, stream>>>(deg, boff, rowstart, cursor, NN);
    fill_kernel<<<NE / 256, 256, 0, stream>>>(src, dst, cursor, csr_src, csr_e, NE);
    ea_gather_kernel<<<NN / 16, 256, 0, stream>>>(edge_attr, rowstart, csr_e, ea_agg, NN);

    // h = x @ Wx + bx  (fp32 in, slice-major bf16 out)
    gemm_kernel<128, 128, false, true, false, false, true><<<GEMM_GRID, 256, 0, stream>>>(
        x, wx_s, bx, h, nullptr, NN);

    for (int l = 0; l < NLAYER; ++l) {
        float* stats_l = stats + l * 256;
        agg_kernel<<<NCHUNK * 8, 256, 0, stream>>>(
            h, rowstart, csr_src, ea_agg, We + l * EDGE_F * EMB, be + l * EMB, aggb);
        gemm_kernel<128, 256, true, false, false, true, false><<<GEMM_GRID, 256, 0, stream>>>(
            aggb, w1_s + l * 32768, b1 + l * 2 * EMB, t1, nullptr, NN);
        if (l < NLAYER - 1)
            gemm_kernel<256, 128, false, false, true, false, true><<<GEMM_GRID, 256, 0, stream>>>(
                t1, w2_s + l * 32768, b2 + l * EMB, h2b, psum, NN);
        else
            gemm_kernel<256, 128, false, false, true, false, false><<<GEMM_GRID, 256, 0, stream>>>(
                t1, w2_s + l * 32768, b2 + l * EMB, h2b, psum, NN);
        reduce_stats_kernel<<<1, 256, 0, stream>>>(psum, stats_l, GEMM_GRID);
        norm_kernel<<<1024, 256, 0, stream>>>(
            h2b, stats_l, stats_l + 128, gamma + l * EMB, beta + l * EMB,
            (l == NLAYER - 1) ? d_out : (void*)h,
            (l < NLAYER - 1) ? 1 : 0, (l == NLAYER - 1) ? 1 : 0,
            (l < NLAYER - 1) ? 1 : 0);
    }
}

// Round 8
// 838.299 us; speedup vs baseline: 1.4996x; 1.4996x over previous
//
#include <hip/hip_runtime.h>

typedef __bf16 bf16;
typedef __bf16 bf16x2 __attribute__((ext_vector_type(2)));
typedef __bf16 bf16x4 __attribute__((ext_vector_type(4)));
typedef __bf16 bf16x8 __attribute__((ext_vector_type(8)));
typedef float f32x4 __attribute__((ext_vector_type(4)));

#define NN 50000
#define NE 800000
#define EMB 128
#define EDGE_F 16
#define NLAYER 5
#define SCAN_BLOCKS 196   // ceil(50000/256)
// slice-major layout: [8 slices][NN nodes][16 ch], slice = ch >> 4
#define NPC 64                              // nodes per agg block (256 thr / 4 lanes)
#define NCHUNK ((NN + NPC - 1) / NPC)       // 782
#define GEMM_GRID 391                       // B-stationary GEMM blocks
#define RS1 49                              // stage-1 reduce blocks (49*8 >= 391)

// ---------------------------------------------------------------------------
// Weight swizzle + fp32->bf16: row-major [K][N] -> [(k/32)][n][k%32] so an
// MFMA B-fragment (n = lane&15, k = (lane>>4)*8 + j) is one contiguous 16B.
// ---------------------------------------------------------------------------
__global__ __launch_bounds__(256) void swz_kernel(
    const float* __restrict__ Wx, const float* __restrict__ W1,
    const float* __restrict__ W2,
    bf16* __restrict__ wx_s, bf16* __restrict__ w1_s, bf16* __restrict__ w2_s)
{
    int t = blockIdx.x * 256 + threadIdx.x;
    if (t < 16384) {                                   // Wx: K=128,N=128
        int k = t >> 7, n = t & 127;
        wx_s[(((k >> 5) << 7) + n) * 32 + (k & 31)] = (bf16)Wx[t];
    } else if (t < 16384 + 163840) {                   // W1: 5 x (K=128,N=256)
        int u = t - 16384;
        int l = u / 32768, r = u % 32768;
        int k = r >> 8, n = r & 255;
        w1_s[l * 32768 + (((k >> 5) << 8) + n) * 32 + (k & 31)] = (bf16)W1[u];
    } else if (t < 16384 + 327680) {                   // W2: 5 x (K=256,N=128)
        int u = t - (16384 + 163840);
        int l = u / 32768, r = u % 32768;
        int k = r >> 7, n = r & 127;
        w2_s[l * 32768 + (((k >> 5) << 7) + n) * 32 + (k & 31)] = (bf16)W2[u];
    }
}

// ---------------------------------------------------------------------------
// CSR build: count -> hierarchical scan -> fill
// ---------------------------------------------------------------------------
__global__ void count_kernel(const int* __restrict__ dst, int* __restrict__ deg, int nE)
{
    int e = blockIdx.x * 256 + threadIdx.x;
    if (e < nE) atomicAdd(&deg[dst[e]], 1);
}

__global__ __launch_bounds__(256) void deg_bsum_kernel(
    const int* __restrict__ deg, int* __restrict__ bsum, int n)
{
    __shared__ int red[256];
    int i = blockIdx.x * 256 + threadIdx.x;
    red[threadIdx.x] = (i < n) ? deg[i] : 0;
    __syncthreads();
    for (int s = 128; s > 0; s >>= 1) {
        if (threadIdx.x < s) red[threadIdx.x] += red[threadIdx.x + s];
        __syncthreads();
    }
    if (threadIdx.x == 0) bsum[blockIdx.x] = red[0];
}

__global__ __launch_bounds__(256) void bsum_scan_kernel(
    const int* __restrict__ bsum, int* __restrict__ boff,
    int* __restrict__ rowstart, int nb, int n)
{
    __shared__ int v[256];
    int t = threadIdx.x;
    v[t] = (t < nb) ? bsum[t] : 0;
    __syncthreads();
    if (t == 0) {
        int r = 0;
        for (int i = 0; i < nb; ++i) { int x = v[i]; v[i] = r; r += x; }
        rowstart[n] = r;
    }
    __syncthreads();
    if (t < nb) boff[t] = v[t];
}

__global__ __launch_bounds__(256) void chunk_scan_kernel(
    const int* __restrict__ deg, const int* __restrict__ boff,
    int* __restrict__ rowstart, int* __restrict__ cursor, int n)
{
    __shared__ int v[256];
    int t = threadIdx.x;
    int i = blockIdx.x * 256 + t;
    int x = (i < n) ? deg[i] : 0;
    v[t] = x;
    __syncthreads();
    for (int s = 1; s < 256; s <<= 1) {
        int add = (t >= s) ? v[t - s] : 0;
        __syncthreads();
        v[t] += add;
        __syncthreads();
    }
    int ex = v[t] - x + boff[blockIdx.x];
    if (i < n) { rowstart[i] = ex; cursor[i] = ex; }
}

__global__ void fill_kernel(const int* __restrict__ src, const int* __restrict__ dst,
                            int* __restrict__ cursor, int* __restrict__ csr_src,
                            int* __restrict__ csr_e, int nE)
{
    int e = blockIdx.x * 256 + threadIdx.x;
    if (e < nE) {
        int d = dst[e];
        int pos = atomicAdd(&cursor[d], 1);
        csr_src[pos] = src[e];
        csr_e[pos] = e;
    }
}

// ---------------------------------------------------------------------------
// ea_agg[i][f] = sum over in-edges of edge_attr[e][f]. fp64 accumulation so
// the (nondeterministic) CSR slot order cannot perturb the fp32 result.
// ---------------------------------------------------------------------------
__global__ __launch_bounds__(256) void ea_gather_kernel(
    const float* __restrict__ edge_attr, const int* __restrict__ rowstart,
    const int* __restrict__ csr_e, float* __restrict__ ea_agg, int n)
{
    int node = blockIdx.x * 16 + (threadIdx.x >> 4);
    int f = threadIdx.x & 15;
    if (node >= n) return;
    int rs = rowstart[node], re = rowstart[node + 1];
    double a = 0.0;
    for (int j = rs; j < re; ++j) {
        int e = csr_e[j];
        a += (double)edge_attr[(size_t)e * EDGE_F + f];
    }
    ea_agg[node * EDGE_F + f] = (float)a;
}

// ---------------------------------------------------------------------------
// agg[slice][i][c] = sum_{e:dst=i} h[src_e] + h[i] + ea_agg[i]@We + (deg+1)*be
// Deterministic blockIdx%8 slicing; fp64 edge accumulation -> bit-
// deterministic under CSR-order races. 4 lanes/node, 64 nodes/block.
// ---------------------------------------------------------------------------
__global__ __launch_bounds__(256) void agg_kernel(
    const bf16* __restrict__ hsm, const int* __restrict__ rowstart,
    const int* __restrict__ csr_src, const float* __restrict__ ea_agg,
    const float* __restrict__ We_l, const float* __restrict__ be_l,
    bf16* __restrict__ aggb)
{
    const int tid = threadIdx.x;
    const int slice = blockIdx.x & 7;
    const int chunk = blockIdx.x >> 3;
    const int node = chunk * NPC + (tid >> 2);
    const int ql = tid & 3;                  // 4 channels per lane
    if (node >= NN) return;
    const size_t sbase = (size_t)slice * NN * 16;
    const bf16* hs = hsm + sbase + ql * 4;
    const int cs = slice * 16 + ql * 4;      // global channel base
    const int rs = rowstart[node], re = rowstart[node + 1];

    double d0 = 0.0, d1 = 0.0, d2 = 0.0, d3 = 0.0;
    int j = rs;
    for (; j + 4 <= re; j += 4) {
        int s0 = csr_src[j],     s1 = csr_src[j + 1];
        int s2 = csr_src[j + 2], s3 = csr_src[j + 3];
        bf16x4 r0 = *(const bf16x4*)(hs + (size_t)s0 * 16);
        bf16x4 r1 = *(const bf16x4*)(hs + (size_t)s1 * 16);
        bf16x4 r2 = *(const bf16x4*)(hs + (size_t)s2 * 16);
        bf16x4 r3 = *(const bf16x4*)(hs + (size_t)s3 * 16);
        d0 += ((double)(float)r0.x + (double)(float)r1.x)
            + ((double)(float)r2.x + (double)(float)r3.x);
        d1 += ((double)(float)r0.y + (double)(float)r1.y)
            + ((double)(float)r2.y + (double)(float)r3.y);
        d2 += ((double)(float)r0.z + (double)(float)r1.z)
            + ((double)(float)r2.z + (double)(float)r3.z);
        d3 += ((double)(float)r0.w + (double)(float)r1.w)
            + ((double)(float)r2.w + (double)(float)r3.w);
    }
    for (; j < re; ++j) {
        int s = csr_src[j];
        bf16x4 rv = *(const bf16x4*)(hs + (size_t)s * 16);
        d0 += (double)(float)rv.x; d1 += (double)(float)rv.y;
        d2 += (double)(float)rv.z; d3 += (double)(float)rv.w;
    }
    {   // self loop
        bf16x4 rv = *(const bf16x4*)(hs + (size_t)node * 16);
        d0 += (double)(float)rv.x; d1 += (double)(float)rv.y;
        d2 += (double)(float)rv.z; d3 += (double)(float)rv.w;
    }
    f32x4 acc;
    acc.x = (float)d0; acc.y = (float)d1; acc.z = (float)d2; acc.w = (float)d3;
    // + ea_agg[node] @ We[:, cs..cs+3]  (We row-major [16][128], L1-hot)
    const float* ea = ea_agg + (size_t)node * EDGE_F;
#pragma unroll
    for (int f = 0; f < EDGE_F; ++f) {
        f32x4 w = *(const f32x4*)(We_l + f * EMB + cs);
        float ef = ea[f];
        acc.x += ef * w.x; acc.y += ef * w.y;
        acc.z += ef * w.z; acc.w += ef * w.w;
    }
    const f32x4 bev = *(const f32x4*)(be_l + cs);
    float dp1 = (float)(re - rs + 1);
    acc.x += dp1 * bev.x; acc.y += dp1 * bev.y;
    acc.z += dp1 * bev.z; acc.w += dp1 * bev.w;
    bf16x4 o;
    o.x = (bf16)acc.x; o.y = (bf16)acc.y; o.z = (bf16)acc.z; o.w = (bf16)acc.w;
    *(bf16x4*)(aggb + sbase + (size_t)node * 16 + ql * 4) = o;
}

// ---------------------------------------------------------------------------
// B-STATIONARY GEMM: whole pre-swizzled B (<=64KB) staged to LDS once per
// block; waves grid-stride over 16-row strips (3125 strips, no guards).
// STATS: deterministic register accumulation per block -> psum row.
// ---------------------------------------------------------------------------
template <int K, int N, bool RELU, bool AFP32, bool STATS, bool ASM, bool OSM>
__global__ __launch_bounds__(256) void gemm_kernel(
    const void* __restrict__ Ap, const bf16* __restrict__ Bswz,
    const float* __restrict__ bias, bf16* __restrict__ outp,
    float* __restrict__ psum, int M)
{
    __shared__ bf16 Bl[K * N];
    __shared__ float lstat[STATS ? 1024 : 1];
    for (int i = threadIdx.x; i < K * N / 8; i += 256)
        ((bf16x8*)Bl)[i] = ((const bf16x8*)Bswz)[i];
    __syncthreads();

    const int lane = threadIdx.x & 63;
    const int wave = threadIdx.x >> 6;
    const int m = lane & 15, q = lane >> 4;
    constexpr int NF = N / 16, KB = K / 32;
    const int S = M >> 4;                    // 3125 strips

    float sacc1[STATS ? NF : 1];
    float sacc2[STATS ? NF : 1];
    if constexpr (STATS) {
#pragma unroll
        for (int f = 0; f < NF; ++f) { sacc1[f] = 0.f; sacc2[f] = 0.f; }
    }

    for (int s = blockIdx.x * 4 + wave; s < S; s += gridDim.x * 4) {
        const int m0 = s * 16;
        f32x4 acc[NF];
#pragma unroll
        for (int f = 0; f < NF; ++f) acc[f] = 0.f;

#pragma unroll
        for (int kb = 0; kb < KB; ++kb) {
            bf16x8 a;
            if constexpr (AFP32) {
                const float* ar = (const float*)Ap + (size_t)(m0 + m) * K + kb * 32 + q * 8;
                f32x4 v0 = *(const f32x4*)ar;
                f32x4 v1 = *(const f32x4*)(ar + 4);
#pragma unroll
                for (int jj = 0; jj < 4; ++jj) { a[jj] = (bf16)v0[jj]; a[4 + jj] = (bf16)v1[jj]; }
            } else if constexpr (ASM) {
                // slice-major A: channels kb*32+q*8 live in slice 2kb+(q>>1)
                const bf16* ar = (const bf16*)Ap
                    + ((size_t)(kb * 2 + (q >> 1)) * M + (m0 + m)) * 16 + (q & 1) * 8;
                a = *(const bf16x8*)ar;
            } else {
                const bf16* ar = (const bf16*)Ap + (size_t)(m0 + m) * K + kb * 32 + q * 8;
                a = *(const bf16x8*)ar;
            }
#pragma unroll
            for (int f = 0; f < NF; ++f) {
                bf16x8 b = *(const bf16x8*)(Bl + (size_t)(kb * N + f * 16 + m) * 32 + q * 8);
                acc[f] = __builtin_amdgcn_mfma_f32_16x16x32_bf16(a, b, acc[f], 0, 0, 0);
            }
        }

#pragma unroll
        for (int f = 0; f < NF; ++f) {
            const int col = f * 16 + m;
            float bv = bias[col];
#pragma unroll
            for (int r = 0; r < 4; ++r) {
                float v = acc[f][r] + bv;
                if (RELU) v = fmaxf(v, 0.f);
                int row = m0 + q * 4 + r;
                if constexpr (OSM)
                    outp[((size_t)f * M + row) * 16 + m] = (bf16)v;
                else
                    outp[(size_t)row * N + col] = (bf16)v;
                if constexpr (STATS) { sacc1[f] += v; sacc2[f] += v * v; }
            }
        }
    }

    if constexpr (STATS) {
#pragma unroll
        for (int f = 0; f < NF; ++f) {
            float s1 = sacc1[f], s2 = sacc2[f];
            s1 += __shfl_xor(s1, 16); s1 += __shfl_xor(s1, 32);
            s2 += __shfl_xor(s2, 16); s2 += __shfl_xor(s2, 32);
            if (q == 0) {
                lstat[wave * 128 + f * 16 + m] = s1;
                lstat[512 + wave * 128 + f * 16 + m] = s2;
            }
        }
        __syncthreads();
        int t = threadIdx.x;
        if (t < 128) {
            float s = lstat[t] + lstat[128 + t] + lstat[256 + t] + lstat[384 + t];
            float ssq = lstat[512 + t] + lstat[640 + t] + lstat[768 + t] + lstat[896 + t];
            psum[(size_t)blockIdx.x * 256 + t] = s;
            psum[(size_t)blockIdx.x * 256 + 128 + t] = ssq;
        }
    }
}

// ---------------------------------------------------------------------------
// Two-stage deterministic stats reduce (round-7: 1-block serial version was
// 94us/layer — one outstanding load x 391 iters of ~580cyc cross-XCD latency).
// Stage 1: 49 blocks x 8 unrolled independent loads. Stage 2: 1 block, 8
// rolling accumulators, fixed combine tree -> bit-deterministic.
// ---------------------------------------------------------------------------
__global__ __launch_bounds__(256) void reduce_stats1_kernel(
    const float* __restrict__ psum, float* __restrict__ partial, int nblk)
{
    int c = threadIdx.x;
    int r0 = blockIdx.x * 8;
    float a[8];
#pragma unroll
    for (int k = 0; k < 8; ++k) {
        int r = r0 + k;
        a[k] = (r < nblk) ? psum[(size_t)r * 256 + c] : 0.f;
    }
    partial[(size_t)blockIdx.x * 256 + c] =
        ((a[0] + a[1]) + (a[2] + a[3])) + ((a[4] + a[5]) + (a[6] + a[7]));
}

__global__ __launch_bounds__(256) void reduce_stats2_kernel(
    const float* __restrict__ partial, float* __restrict__ stats, int np)
{
    int c = threadIdx.x;
    float a[8];
#pragma unroll
    for (int k = 0; k < 8; ++k) a[k] = 0.f;
    int r = 0;
    for (; r + 8 <= np; r += 8) {
#pragma unroll
        for (int k = 0; k < 8; ++k) a[k] += partial[(size_t)(r + k) * 256 + c];
    }
    for (int k = 0; r + k < np; ++k) a[k] += partial[(size_t)(r + k) * 256 + c];
    stats[c] = ((a[0] + a[1]) + (a[2] + a[3])) + ((a[4] + a[5]) + (a[6] + a[7]));
}

// ---------------------------------------------------------------------------
// BatchNorm normalize (+optional relu). sm selects slice-major channel decode
// (intermediate layers) vs row-major (final layer, fp32 d_out).
// ---------------------------------------------------------------------------
__global__ __launch_bounds__(256) void norm_kernel(
    const bf16* __restrict__ h2, const float* __restrict__ sums,
    const float* __restrict__ sumsq, const float* __restrict__ gamma,
    const float* __restrict__ beta, void* __restrict__ outp,
    int relu, int out_fp32, int sm)
{
    __shared__ float sc[EMB], sh[EMB];
    int tid = threadIdx.x;
    if (tid < EMB) {
        float inv_n = 1.0f / (float)NN;
        float mean = sums[tid] * inv_n;
        float var = sumsq[tid] * inv_n - mean * mean;
        float s = gamma[tid] * rsqrtf(var + 1e-5f);
        sc[tid] = s;
        sh[tid] = beta[tid] - mean * s;
    }
    __syncthreads();
    const int total4 = NN * (EMB / 4);
    int stride = gridDim.x * blockDim.x;
    for (int i = blockIdx.x * blockDim.x + tid; i < total4; i += stride) {
        bf16x4 hv = ((const bf16x4*)h2)[i];
        int c0;
        if (sm) {
            int o = i * 4;
            int slice = o / (NN * 16);
            c0 = slice * 16 + ((o - slice * (NN * 16)) & 15);
        } else {
            c0 = (i * 4) & (EMB - 1);
        }
        float v0 = (float)hv.x * sc[c0] + sh[c0];
        float v1 = (float)hv.y * sc[c0 + 1] + sh[c0 + 1];
        float v2 = (float)hv.z * sc[c0 + 2] + sh[c0 + 2];
        float v3 = (float)hv.w * sc[c0 + 3] + sh[c0 + 3];
        if (relu) {
            v0 = fmaxf(v0, 0.f); v1 = fmaxf(v1, 0.f);
            v2 = fmaxf(v2, 0.f); v3 = fmaxf(v3, 0.f);
        }
        if (out_fp32) {
            f32x4 o; o.x = v0; o.y = v1; o.z = v2; o.w = v3;
            ((f32x4*)outp)[i] = o;
        } else {
            bf16x4 o;
            o.x = (bf16)v0; o.y = (bf16)v1; o.z = (bf16)v2; o.w = (bf16)v3;
            ((bf16x4*)outp)[i] = o;
        }
    }
}

// ---------------------------------------------------------------------------
extern "C" void kernel_launch(void* const* d_in, const int* in_sizes, int n_in,
                              void* d_out, int out_size, void* d_ws, size_t ws_size,
                              hipStream_t stream)
{
    const float* x         = (const float*)d_in[0];
    const float* edge_attr = (const float*)d_in[1];
    const int*   eidx      = (const int*)d_in[2];
    const float* Wx        = (const float*)d_in[3];
    const float* bx        = (const float*)d_in[4];
    const float* We        = (const float*)d_in[5];
    const float* be        = (const float*)d_in[6];
    const float* W1        = (const float*)d_in[7];
    const float* b1        = (const float*)d_in[8];
    const float* W2        = (const float*)d_in[9];
    const float* b2        = (const float*)d_in[10];
    const float* gamma     = (const float*)d_in[11];
    const float* beta      = (const float*)d_in[12];

    // ---- workspace layout (poisoned 0xAA before every call) ----
    size_t off = 0;
    char* base = (char*)d_ws;
    auto alloc = [&](size_t bytes) -> void* {
        void* p = base + off;
        off += (bytes + 255) & ~(size_t)255;
        return p;
    };
    int*   deg      = (int*)alloc(NN * 4);
    size_t zero_bytes = off;                             // only deg needs zeroing
    float* stats    = (float*)alloc(NLAYER * 256 * 4);   // written (=) by reduce
    int*   rowstart = (int*)alloc((NN + 1) * 4);
    int*   cursor   = (int*)alloc(NN * 4);
    int*   bsum     = (int*)alloc(SCAN_BLOCKS * 4);
    int*   boff     = (int*)alloc(SCAN_BLOCKS * 4);
    int*   csr_src  = (int*)alloc((size_t)NE * 4);
    int*   csr_e    = (int*)alloc((size_t)NE * 4);
    float* ea_agg   = (float*)alloc((size_t)NN * EDGE_F * 4);
    bf16*  h        = (bf16*)alloc((size_t)NN * EMB * 2);   // slice-major
    bf16*  aggb     = (bf16*)alloc((size_t)NN * EMB * 2);   // slice-major
    bf16*  t1       = (bf16*)alloc((size_t)NN * 2 * EMB * 2);
    bf16*  h2b      = (bf16*)alloc((size_t)NN * EMB * 2);   // sm (l<4) / rm (l=4)
    float* psum     = (float*)alloc((size_t)GEMM_GRID * 256 * 4);
    float* partial  = (float*)alloc((size_t)RS1 * 256 * 4);
    bf16*  wx_s     = (bf16*)alloc(16384 * 2);
    bf16*  w1_s     = (bf16*)alloc(163840 * 2);
    bf16*  w2_s     = (bf16*)alloc(163840 * 2);
    (void)ws_size; (void)in_sizes; (void)n_in; (void)out_size;

    const int* src = eidx;
    const int* dst = eidx + NE;

    hipMemsetAsync(d_ws, 0, zero_bytes, stream);

    swz_kernel<<<1344, 256, 0, stream>>>(Wx, W1, W2, wx_s, w1_s, w2_s);
    count_kernel<<<NE / 256, 256, 0, stream>>>(dst, deg, NE);
    deg_bsum_kernel<<<SCAN_BLOCKS, 256, 0, stream>>>(deg, bsum, NN);
    bsum_scan_kernel<<<1, 256, 0, stream>>>(bsum, boff, rowstart, SCAN_BLOCKS, NN);
    chunk_scan_kernel<<<SCAN_BLOCKS, 256, 0, stream>>>(deg, boff, rowstart, cursor, NN);
    fill_kernel<<<NE / 256, 256, 0, stream>>>(src, dst, cursor, csr_src, csr_e, NE);
    ea_gather_kernel<<<NN / 16, 256, 0, stream>>>(edge_attr, rowstart, csr_e, ea_agg, NN);

    // h = x @ Wx + bx  (fp32 in, slice-major bf16 out)
    gemm_kernel<128, 128, false, true, false, false, true><<<GEMM_GRID, 256, 0, stream>>>(
        x, wx_s, bx, h, nullptr, NN);

    for (int l = 0; l < NLAYER; ++l) {
        float* stats_l = stats + l * 256;
        agg_kernel<<<NCHUNK * 8, 256, 0, stream>>>(
            h, rowstart, csr_src, ea_agg, We + l * EDGE_F * EMB, be + l * EMB, aggb);
        gemm_kernel<128, 256, true, false, false, true, false><<<GEMM_GRID, 256, 0, stream>>>(
            aggb, w1_s + l * 32768, b1 + l * 2 * EMB, t1, nullptr, NN);
        if (l < NLAYER - 1)
            gemm_kernel<256, 128, false, false, true, false, true><<<GEMM_GRID, 256, 0, stream>>>(
                t1, w2_s + l * 32768, b2 + l * EMB, h2b, psum, NN);
        else
            gemm_kernel<256, 128, false, false, true, false, false><<<GEMM_GRID, 256, 0, stream>>>(
                t1, w2_s + l * 32768, b2 + l * EMB, h2b, psum, NN);
        reduce_stats1_kernel<<<RS1, 256, 0, stream>>>(psum, partial, GEMM_GRID);
        reduce_stats2_kernel<<<1, 256, 0, stream>>>(partial, stats_l, RS1);
        norm_kernel<<<1024, 256, 0, stream>>>(
            h2b, stats_l, stats_l + 128, gamma + l * EMB, beta + l * EMB,
            (l == NLAYER - 1) ? d_out : (void*)h,
            (l < NLAYER - 1) ? 1 : 0, (l == NLAYER - 1) ? 1 : 0,
            (l < NLAYER - 1) ? 1 : 0);
    }
}